// Round 6
// baseline (736.733 us; speedup 1.0000x reference)
//
#include <hip/hip_runtime.h>
#include <cstdint>

// SparseMoE on MI355X (gfx950). fp32 inputs. B=2,S=2048 -> NTOK=4096 tokens,
// D=1024, E=8, H=4096, top_k=2.
// R6: m201-class GEMM schedule. Evidence: R0-R5 show ALL drain-to-0 variants
// pin at 145-170 us (17-20% MfmaUtil) regardless of tile/BK/ctx/depth; m218
// says counted-vmcnt IS the lever; m201 validates 1-block/CU 8-wave 512-thr
// 128KiB-LDS counted schedule at 62% MfmaUtil on this chip. Structure:
// 256x256 tile, BK=32, 4-slot LDS ring, prefetch distance 3, per step:
//   STAGE(t+3) -> slot[(t+3)&3]; COMPUTE slot[t&3] (32 MFMA, setprio);
//   s_waitcnt vmcnt(8) lgkmcnt(0); s_barrier; sched_barrier(0)
// vmcnt(8) = 2 stages (8 loads) stay in flight across the barrier; stage(t+1)
// is landed by in-order vmcnt retirement (m135). Tail drains 8->4->0.
// R3's counted-vmcnt failure is addressed: 8 waves (2/SIMD), 64 MFMA per
// wave per window, sched_barrier pinning (rule #18).

#define DEV __device__ __forceinline__

typedef __attribute__((ext_vector_type(8))) short short8;   // 8 x bf16
typedef __attribute__((ext_vector_type(4))) float floatx4;  // MFMA accumulator

constexpr int D_ = 1024, E_ = 8, H_ = 4096;
constexpr int NTOK = 4096;
constexpr int CAP  = 4096;
constexpr int TOTSLOT = NTOK * 2;

// ---- workspace layout (bytes); ~160.3 MB, proven available ----
constexpr size_t O_COUNT = 0;
constexpr size_t O_OFFS  = 64;
constexpr size_t O_BTOK  = 128;
constexpr size_t O_BGATE = O_BTOK  + (size_t)E_ * CAP * 4;
constexpr size_t O_PAIR  = O_BGATE + (size_t)E_ * CAP * 4;
constexpr size_t O_XG    = (O_PAIR + (size_t)NTOK * 2 * 4 + 255) & ~(size_t)255;
constexpr size_t O_HBUF  = O_XG   + (size_t)TOTSLOT * D_ * 2;  // 16 MB
constexpr size_t O_YBUF  = O_HBUF + (size_t)TOTSLOT * H_ * 2;  // 64 MB
constexpr size_t O_WT    = O_YBUF + (size_t)TOTSLOT * D_ * 2;  // 16 MB
constexpr size_t WS_NEED = O_WT   + (size_t)E_ * D_ * H_ * 2;  // + 64 MB
// During proj, xg (16 MB) and ybuf (16 MB) hold fp32 partials pb0/pb1.

DEV float b2f(unsigned short u) {
    union { unsigned int i; float f; } v; v.i = ((unsigned int)u) << 16; return v.f;
}
DEV unsigned int f2b(float f) {  // round-to-nearest-even, low 16 bits
    union { float f; unsigned int i; } v; v.f = f;
    unsigned int r = v.i + 0x7fffu + ((v.i >> 16) & 1u);
    return (r >> 16) & 0xffffu;
}
DEV float gelu_tanh(float x) {
    float u = 0.7978845608028654f * (x + 0.044715f * x * x * x);
    u = fminf(fmaxf(u, -20.f), 20.f);
    float e = __expf(2.f * u);
    float t = (e - 1.f) / (e + 1.f);
    return 0.5f * x * (1.f + t);
}

// async global->LDS, 16 B per lane (dest = wave-uniform base + lane*16)
typedef __attribute__((address_space(3))) unsigned int lds_u32_t;
typedef const __attribute__((address_space(1))) unsigned int g_u32_t;
DEV void gload16(const unsigned short* g, const unsigned short* l) {
    __builtin_amdgcn_global_load_lds((g_u32_t*)(size_t)g,
                                     (lds_u32_t*)(unsigned int)(size_t)l, 16, 0, 0);
}

// ---------------------------------------------------------------------------
__global__ __launch_bounds__(64) void zero_counts(int* counts) {
    if (threadIdx.x < E_) counts[threadIdx.x] = 0;
}

// Router: one wave per token, fp64 accumulation (minimizes top-k flips vs the
// np fp32 reference — the dominant correctness risk; proven).
__global__ __launch_bounds__(256) void router_kernel(
    const float* __restrict__ x, const float* __restrict__ noise,
    const float* __restrict__ w_route, const float* __restrict__ b_route,
    const float* __restrict__ w_noise, const float* __restrict__ b_noise,
    float* __restrict__ out,  // gate1 at element offset NTOK*D_
    int* counts, int* btok, float* bgate, int* pairs)
{
    int wave = threadIdx.x >> 6, lane = threadIdx.x & 63;
    int t = blockIdx.x * 4 + wave;

    double racc[E_], nacc[E_];
#pragma unroll
    for (int e = 0; e < E_; e++) { racc[e] = 0.0; nacc[e] = 0.0; }

#pragma unroll 4
    for (int i = 0; i < D_ / 64; i++) {
        int j = i * 64 + lane;
        float xv = x[(size_t)t * D_ + j];
        const float* wr = w_route + (size_t)j * E_;
        const float* wn = w_noise + (size_t)j * E_;
        float4 a0 = ((const float4*)wr)[0], a1 = ((const float4*)wr)[1];
        float4 c0 = ((const float4*)wn)[0], c1 = ((const float4*)wn)[1];
        const float rv[8] = {a0.x,a0.y,a0.z,a0.w,a1.x,a1.y,a1.z,a1.w};
        const float nv[8] = {c0.x,c0.y,c0.z,c0.w,c1.x,c1.y,c1.z,c1.w};
#pragma unroll
        for (int e = 0; e < E_; e++) {
            racc[e] += (double)(xv * rv[e]);
            nacc[e] += (double)(xv * nv[e]);
        }
    }
#pragma unroll
    for (int off = 32; off > 0; off >>= 1)
#pragma unroll
        for (int e = 0; e < E_; e++) {
            racc[e] += __shfl_down(racc[e], off);
            nacc[e] += __shfl_down(nacc[e], off);
        }

    if (lane == 0) {
        double nz[E_];
#pragma unroll
        for (int e = 0; e < E_; e++) {
            double lg = racc[e] + (double)b_route[e];
            double nl = nacc[e] + (double)b_noise[e];
            double sp = (nl > 0.0) ? nl + log1p(exp(-nl)) : log1p(exp(nl));
            nz[e] = lg + (double)noise[(size_t)t * E_ + e] * sp;
        }
        double mx = nz[0];
#pragma unroll
        for (int e = 1; e < E_; e++) mx = fmax(mx, nz[e]);
        double se = 0.0, ex[E_];
#pragma unroll
        for (int e = 0; e < E_; e++) { ex[e] = exp(nz[e] - mx); se += ex[e]; }
#pragma unroll
        for (int e = 0; e < E_; e++)
            out[(size_t)NTOK * D_ + (size_t)t * E_ + e] = (float)(ex[e] / se);
        // top-2 (strict > keeps lower index on ties, matching lax.top_k)
        double v0 = -1e300, v1 = -1e300; int i0 = 0, i1 = 0;
#pragma unroll
        for (int e = 0; e < E_; e++) {
            double v = nz[e];
            if (v > v0) { v1 = v0; i1 = i0; v0 = v; i0 = e; }
            else if (v > v1) { v1 = v; i1 = e; }
        }
        double g0 = 1.0 / (1.0 + exp(v1 - v0));
        float  g1 = (float)(1.0 - g0);
        int l0 = atomicAdd(&counts[i0], 1);
        int l1 = atomicAdd(&counts[i1], 1);
        btok[i0 * CAP + l0] = t;  bgate[i0 * CAP + l0] = (float)g0;
        btok[i1 * CAP + l1] = t;  bgate[i1 * CAP + l1] = g1;
        pairs[2 * t]     = (i0 << 16) | l0;
        pairs[2 * t + 1] = (i1 << 16) | l1;
    }
}

__global__ __launch_bounds__(64) void offsets_kernel(const int* counts, int* offs) {
    if (threadIdx.x == 0) {
        int a = 0;
        for (int e = 0; e < E_; e++) { offs[e] = a; a += counts[e]; }
        offs[E_] = a;
    }
}

// Scatter x rows (fp32 -> bf16) to both selected slots. One block per token.
__global__ __launch_bounds__(256) void gather_x(
    const float* __restrict__ x, const int* __restrict__ pairs,
    const int* __restrict__ offs, unsigned short* __restrict__ xg)
{
    int t = blockIdx.x;
    int c = threadIdx.x * 4;
    float4 v = *(const float4*)(x + (size_t)t * D_ + c);
    uint2 o;
    o.x = f2b(v.x) | (f2b(v.y) << 16);
    o.y = f2b(v.z) | (f2b(v.w) << 16);
    int p0 = pairs[2 * t], p1 = pairs[2 * t + 1];
    size_t r0 = (size_t)(offs[p0 >> 16] + (p0 & 0xffff)) * D_;
    size_t r1 = (size_t)(offs[p1 >> 16] + (p1 & 0xffff)) * D_;
    *(uint2*)(xg + r0 + c) = o;
    *(uint2*)(xg + r1 + c) = o;
}

// transpose+convert: w [E][K][N] fp32 -> wT [E][N][K] bf16. 64x64 LDS tiles.
__global__ __launch_bounds__(256) void transpose_w(
    const float* __restrict__ w, unsigned short* __restrict__ wT, int K, int N)
{
    __shared__ unsigned short t[64][65];
    const int e  = blockIdx.z;
    const int k0 = blockIdx.y * 64;
    const int n0 = blockIdx.x * 64;
    const int r  = threadIdx.x >> 2;          // 0..63
    const int c4 = (threadIdx.x & 3) * 16;    // 0,16,32,48
    const float* src = w + ((size_t)e * K + k0 + r) * N + n0 + c4;
#pragma unroll
    for (int i = 0; i < 4; i++) {
        float4 v = ((const float4*)src)[i];
        t[r][c4 + 4*i + 0] = (unsigned short)f2b(v.x);
        t[r][c4 + 4*i + 1] = (unsigned short)f2b(v.y);
        t[r][c4 + 4*i + 2] = (unsigned short)f2b(v.z);
        t[r][c4 + 4*i + 3] = (unsigned short)f2b(v.w);
    }
    __syncthreads();
    unsigned short* dstp = wT + ((size_t)e * N + n0 + r) * K + k0 + c4;
    unsigned short tmp[16];
#pragma unroll
    for (int i = 0; i < 16; i++) tmp[i] = t[c4 + i][r];
#pragma unroll
    for (int h = 0; h < 2; h++) {
        uint4 pk;
        pk.x = (unsigned int)tmp[8*h+0] | ((unsigned int)tmp[8*h+1] << 16);
        pk.y = (unsigned int)tmp[8*h+2] | ((unsigned int)tmp[8*h+3] << 16);
        pk.z = (unsigned int)tmp[8*h+4] | ((unsigned int)tmp[8*h+5] << 16);
        pk.w = (unsigned int)tmp[8*h+6] | ((unsigned int)tmp[8*h+7] << 16);
        ((uint4*)dstp)[h] = pk;
    }
}

// zero the fp32 partial buffer (both 16 MB halves); runs after FC frees xg.
__global__ __launch_bounds__(256) void zero_pbuf(float* pb0, float* pb1) {
    size_t i = ((size_t)blockIdx.x * 256 + threadIdx.x) * 4;
    float4 z = {0.f, 0.f, 0.f, 0.f};
    *(float4*)(pb0 + i) = z;
    *(float4*)(pb1 + i) = z;
}

// ---- grouped GEMM: 256x256 tile, BK=32, 4-slot ring, counted vmcnt ---------
// 8 waves (2M x 4N, per-wave 128x64 out), 16x16x32 bf16 MFMA.
// LDS: 4 slots x (A 256x32 + B 256x32) = 128 KiB dynamic.
// Swizzle (R5-proven, 0 conflicts): LDS k-slot s of row r holds global chunk
// s ^ ((r>>1)&3); read &T[R*32 + ((quad ^ ((R>>1)&3))*8)].
// proj: split-K=2 folded into XCD index (xcd&3 = n-tile, xcd>>2 = k-half),
// fp32 atomicAdd partials into pb0/pb1 (bias added by kh==0 only).
template <int KD, int ND, bool FC, int KHALVES>
__global__ __launch_bounds__(512, 2) void moe_gemm8w(
    const unsigned short* __restrict__ A,    // [TOTSLOT][KD] bf16 (xg or hbuf)
    const unsigned short* __restrict__ wT,   // [E][ND][KD] bf16
    const float* __restrict__ bias32,        // [E][ND] fp32 (direct input)
    unsigned short* __restrict__ dstBf,      // FC: [TOTSLOT][ND] bf16
    float* __restrict__ pb0, float* __restrict__ pb1,  // proj fp32 partials
    const int* __restrict__ counts, const int* __restrict__ offs,
    const float* __restrict__ bgate)
{
    constexpr int BM = 256, BN = 256, BK = 32;
    constexpr int SEG  = (BM + BN) * BK;     // 16384 shorts = 32 KiB per slot
    constexpr int BOFF = BM * BK;            // 8192 shorts
    extern __shared__ unsigned short smem[]; // 4 slots = 128 KiB

    const int lin = blockIdx.x;
    const int xcd = lin & 7, slot = lin >> 3;
    int e, mt, nt, kh;
    if (FC) {            // ND=4096: 16 n-tiles of 256, 2 per XCD
        nt = xcd * 2 + (slot & 1);
        mt = (slot >> 1) & 15;
        e  = slot >> 5;
        kh = 0;
    } else {             // ND=1024: 4 n-tiles; XCD = (n-tile, k-half) combo
        nt = xcd & 3;
        kh = xcd >> 2;
        mt = slot & 15;
        e  = slot >> 4;
    }
    const int cnt = counts[e];
    const int m0 = mt * BM;
    if (m0 >= cnt) return;
    const int n0 = nt * BN;
    const int off = offs[e];
    constexpr int KB = KD / KHALVES;         // k-range per block
    constexpr int nk = KB / BK;              // FC: 32, proj: 64 (>= 4)
    const int kbase = (KHALVES > 1) ? kh * KB : 0;

    const int tid = threadIdx.x;
    const int waveid = tid >> 6, lane = tid & 63;
    const int srow16 = lane >> 2;            // row within 16-row chunk
    const int sslot  = lane & 3;             // k-slot (8 shorts = 16 B)

    // staging: per wave 2 A-chunks + 2 B-chunks; chunk = 16 rows x 32 shorts
    const unsigned short* aAddr[2];
    const unsigned short* bAddr[2];
#pragma unroll
    for (int c = 0; c < 2; c++) {
        const int rl = (waveid * 2 + c) * 16 + srow16;   // tile-local row
        const int g  = sslot ^ ((rl >> 1) & 3);          // pre-swizzled chunk
        int ar = m0 + rl;
        if (ar > cnt - 1) ar = cnt - 1;
        aAddr[c] = A + (size_t)(off + ar) * KD + kbase + g * 8;
        const int br = n0 + rl;
        bAddr[c] = wT + ((size_t)e * ND + br) * KD + kbase + g * 8;
    }

    const int wm = (waveid >> 2) * 128;      // 2 wave-rows in M
    const int wn = (waveid & 3) * 64;        // 4 wave-cols in N
    const int lrow = lane & 15, quad = lane >> 4;

    floatx4 acc[8][4];
#pragma unroll
    for (int fm = 0; fm < 8; fm++)
#pragma unroll
        for (int fn = 0; fn < 4; fn++) acc[fm][fn] = (floatx4)0.f;

#define STAGE(K_, S_) {                                                      \
    unsigned short* bs_ = smem + (S_) * SEG;                                 \
    const int ko_ = (K_) * BK;                                               \
    _Pragma("unroll")                                                        \
    for (int c = 0; c < 2; c++) {                                            \
        gload16(aAddr[c] + ko_, &bs_[(waveid * 2 + c) * 512]);               \
        gload16(bAddr[c] + ko_, &bs_[BOFF + (waveid * 2 + c) * 512]);        \
    } }

#define COMPUTE(S_) {                                                        \
    const unsigned short* As_ = smem + (S_) * SEG;                           \
    const unsigned short* Bs_ = As_ + BOFF;                                  \
    short8 af_[8], bf_[4];                                                   \
    _Pragma("unroll")                                                        \
    for (int f = 0; f < 8; f++) {                                            \
        const int R_ = wm + f * 16 + lrow;                                   \
        af_[f] = *(const short8*)&As_[R_ * 32 + ((quad ^ ((R_ >> 1) & 3)) * 8)]; \
    }                                                                        \
    _Pragma("unroll")                                                        \
    for (int f = 0; f < 4; f++) {                                            \
        const int R_ = wn + f * 16 + lrow;                                   \
        bf_[f] = *(const short8*)&Bs_[R_ * 32 + ((quad ^ ((R_ >> 1) & 3)) * 8)]; \
    }                                                                        \
    __builtin_amdgcn_s_setprio(1);                                           \
    _Pragma("unroll")                                                        \
    for (int fm = 0; fm < 8; fm++)                                           \
        _Pragma("unroll")                                                    \
        for (int fn = 0; fn < 4; fn++)                                       \
            acc[fm][fn] = __builtin_amdgcn_mfma_f32_16x16x32_bf16(           \
                af_[fm], bf_[fn], acc[fm][fn], 0, 0, 0);                     \
    __builtin_amdgcn_s_setprio(0); }

#define WAITBAR(VM_) {                                                       \
    __builtin_amdgcn_sched_barrier(0);                                       \
    asm volatile("s_waitcnt vmcnt(" #VM_ ") lgkmcnt(0)" ::: "memory");       \
    __builtin_amdgcn_s_barrier();                                            \
    __builtin_amdgcn_sched_barrier(0); }

    // prologue: stage K-tiles 0,1,2 into slots 0,1,2 (12 loads/thread)
    STAGE(0, 0); STAGE(1, 1); STAGE(2, 2);
    WAITBAR(8);                              // stage(0) landed; 1,2 in flight

    // main loop: stage(t+3) || compute(t); stage(t+1) guaranteed landed
    for (int t = 0; t < nk - 3; ++t) {
        STAGE(t + 3, (t + 3) & 3);
        COMPUTE(t & 3);
        WAITBAR(8);                          // 2 newest stages stay in flight
    }
    // tail: drain 8 -> 4 -> 0
    COMPUTE((nk - 3) & 3);
    WAITBAR(4);
    COMPUTE((nk - 2) & 3);
    WAITBAR(0);
    COMPUTE((nk - 1) & 3);

#undef STAGE
#undef COMPUTE
#undef WAITBAR

    // Epilogue. C/D layout: col = lane&15, row = quad*4 + reg.
    const int gc = n0 + wn + lrow;
    float bcol[4];
#pragma unroll
    for (int fn = 0; fn < 4; fn++) bcol[fn] = bias32[(size_t)e * ND + gc + fn * 16];

#pragma unroll
    for (int fm = 0; fm < 8; fm++) {
        int srow0 = m0 + wm + fm * 16 + quad * 4;
#pragma unroll
        for (int r = 0; r < 4; r++) {
            int srow = srow0 + r;
            if (srow < cnt) {
                const int oslot = off + srow;
                if (FC) {
                    size_t base = (size_t)oslot * ND;
#pragma unroll
                    for (int fn = 0; fn < 4; fn++) {
                        float v = acc[fm][fn][r] + bcol[fn];
                        dstBf[base + gc + fn * 16] = (unsigned short)f2b(gelu_tanh(v));
                    }
                } else {
                    float gt = bgate[e * CAP + srow];
                    float* pb = (oslot < NTOK)
                        ? pb0 + (size_t)oslot * D_
                        : pb1 + (size_t)(oslot - NTOK) * D_;
#pragma unroll
                    for (int fn = 0; fn < 4; fn++) {
                        float v = (acc[fm][fn][r] + (kh == 0 ? bcol[fn] : 0.f)) * gt;
                        atomicAdd(&pb[gc + fn * 16], v);
                    }
                }
            }
        }
    }
}

// out[t] = pbuf[slot0(t)] + pbuf[slot1(t)]  (gates+bias already applied)
__global__ __launch_bounds__(256) void combine_kernel(
    const float* __restrict__ pb0, const float* __restrict__ pb1,
    const int* __restrict__ pairs, const int* __restrict__ offs,
    float* __restrict__ out)
{
    int t = blockIdx.x;
    int p0 = pairs[2 * t], p1 = pairs[2 * t + 1];
    int s0 = offs[p0 >> 16] + (p0 & 0xffff);
    int s1 = offs[p1 >> 16] + (p1 & 0xffff);
    int c = threadIdx.x * 4;
    const float* a = (s0 < NTOK ? pb0 + (size_t)s0 * D_
                                : pb1 + (size_t)(s0 - NTOK) * D_) + c;
    const float* b = (s1 < NTOK ? pb0 + (size_t)s1 * D_
                                : pb1 + (size_t)(s1 - NTOK) * D_) + c;
    float4 va = *(const float4*)a;
    float4 vb = *(const float4*)b;
    float4 o;
    o.x = va.x + vb.x; o.y = va.y + vb.y; o.z = va.z + vb.z; o.w = va.w + vb.w;
    *(float4*)(out + (size_t)t * D_ + c) = o;
}

// ---------------------------------------------------------------------------
extern "C" void kernel_launch(void* const* d_in, const int* in_sizes, int n_in,
                              void* d_out, int out_size, void* d_ws, size_t ws_size,
                              hipStream_t stream) {
    if (ws_size < WS_NEED) return;  // diagnostic: output stays 0

    const float* x       = (const float*)d_in[0];
    const float* noise   = (const float*)d_in[1];
    const float* w_route = (const float*)d_in[2];
    const float* b_route = (const float*)d_in[3];
    const float* w_noise = (const float*)d_in[4];
    const float* b_noise = (const float*)d_in[5];
    const float* w_fc    = (const float*)d_in[6];
    const float* b_fc    = (const float*)d_in[7];
    const float* w_proj  = (const float*)d_in[8];
    const float* b_proj  = (const float*)d_in[9];

    char* ws = (char*)d_ws;
    int*   counts = (int*)(ws + O_COUNT);
    int*   offs   = (int*)(ws + O_OFFS);
    int*   btok   = (int*)(ws + O_BTOK);
    float* bgate  = (float*)(ws + O_BGATE);
    int*   pairs  = (int*)(ws + O_PAIR);
    unsigned short* xg   = (unsigned short*)(ws + O_XG);
    unsigned short* hbuf = (unsigned short*)(ws + O_HBUF);
    unsigned short* wT   = (unsigned short*)(ws + O_WT);
    // fp32 partial buffers for proj split-K (reuse xg + ybuf regions)
    float* pb0 = (float*)(ws + O_XG);    // slots 0..4095
    float* pb1 = (float*)(ws + O_YBUF);  // slots 4096..8191

    constexpr unsigned GEMM_LDS = 4u * (256u + 256u) * 32u * 2u;  // 128 KiB

    zero_counts<<<dim3(1), dim3(64), 0, stream>>>(counts);
    router_kernel<<<dim3(NTOK / 4), dim3(256), 0, stream>>>(
        x, noise, w_route, b_route, w_noise, b_noise, (float*)d_out,
        counts, btok, bgate, pairs);
    offsets_kernel<<<dim3(1), dim3(64), 0, stream>>>(counts, offs);
    gather_x<<<dim3(NTOK), dim3(256), 0, stream>>>(x, pairs, offs, xg);

    // FC: w_fc [E][D][H] -> wT [E][H][D]; GEMM 256x256, K=1024
    transpose_w<<<dim3(H_ / 64, D_ / 64, E_), dim3(256), 0, stream>>>(w_fc, wT, D_, H_);
    moe_gemm8w<D_, H_, true, 1><<<dim3(8 * 256), dim3(512), GEMM_LDS, stream>>>(
        xg, wT, b_fc, hbuf, pb0, pb1, counts, offs, bgate);

    // zero fp32 partials (xg is free after FC consumed it)
    zero_pbuf<<<dim3(NTOK), dim3(256), 0, stream>>>(pb0, pb1);

    // proj: w_proj [E][H][D] -> wT [E][D][H]; GEMM 256x256, K=4096, split-K=2
    transpose_w<<<dim3(D_ / 64, H_ / 64, E_), dim3(256), 0, stream>>>(w_proj, wT, H_, D_);
    moe_gemm8w<H_, D_, false, 2><<<dim3(8 * 128), dim3(512), GEMM_LDS, stream>>>(
        hbuf, wT, b_proj, nullptr, pb0, pb1, counts, offs, bgate);

    combine_kernel<<<dim3(NTOK), dim3(256), 0, stream>>>(pb0, pb1, pairs, offs, (float*)d_out);
}